// Round 1
// baseline (448.990 us; speedup 1.0000x reference)
//
#include <hip/hip_runtime.h>
#include <stdint.h>

#define N_CL    8
#define C_IN    862
#define SEQ     720
#define SEQP    768            // K padded to 12 x 64 (Wb zero-padded)
#define PRED    336
#define BATCH   64
#define NT      (PRED / 16)    // 21 n-tiles per channel
#define XBSTRIDE ((size_t)C_IN * SEQ)   // x stride between batches (elements)

typedef __attribute__((ext_vector_type(8))) __bf16 bf16x8;
typedef __attribute__((ext_vector_type(4))) float  floatx4;

// ---- Kernel 1: W fp32 [8][336][720] -> bf16 [8][336][768] (zero-padded K) ----
__global__ void wconv_kernel(const float* __restrict__ W, __bf16* __restrict__ Wb) {
  const int row = blockIdx.x;                 // 0 .. 8*336-1
  const float* src = W + (size_t)row * SEQ;
  __bf16* dst = Wb + (size_t)row * SEQP;
  for (int s = threadIdx.x; s < SEQP; s += blockDim.x) {
    float v = (s < SEQ) ? src[s] : 0.0f;
    dst[s] = (__bf16)v;
  }
}

// ---- Kernel 2: per-channel GEMM, NO LDS, NO barriers. ----
// Block = 256 thr (4 waves), one channel. Each wave owns a 16-row m-strip.
// A-fragment (x rows, per-wave private) and B-fragment (W, L2-resident)
// loaded directly from global per MFMA. Removes the per-chunk vmcnt(0)
// + s_barrier drains that made the staged version latency-bound.
__global__ __launch_bounds__(256, 4) void clin_kernel(
    const float* __restrict__ x, const int* __restrict__ clusters,
    const __bf16* __restrict__ Wb, const float* __restrict__ bias,
    float* __restrict__ out) {
  const int c    = blockIdx.x;
  const int cl   = clusters[c];
  const int tid  = threadIdx.x;
  const int wave = tid >> 6;
  const int lane = tid & 63;
  const int q    = lane >> 4;     // quad 0..3 -> k-subgroup
  const int ln   = lane & 15;     // lane-in-quad -> m-row (A) / n-col (B)

  const int mrow  = (wave << 4) + ln;   // batch row 0..63
  const int klane = q << 3;             // per-lane k offset within 32-wide step

  // Per-lane row bases (16B-aligned: XBSTRIDE*4, c*SEQ*4, SEQP*2, klane*4/2 all 16B-multiples)
  const float*  xr = x  + (size_t)mrow * XBSTRIDE + (size_t)c * SEQ + klane;
  const __bf16* wr = Wb + (size_t)cl * PRED * SEQP + (size_t)ln * SEQP + klane;

  floatx4 acc[NT];
#pragma unroll
  for (int t = 0; t < NT; ++t) acc[t] = (floatx4){0.f, 0.f, 0.f, 0.f};

  // Main loop: k0 = 0..672 (22 iters). Max s touched = 672+24+4+3 = 703 < 720, unpredicated.
#pragma unroll 2
  for (int k0 = 0; k0 < 704; k0 += 32) {
    floatx4 af0 = *(const floatx4*)(xr + k0);
    floatx4 af1 = *(const floatx4*)(xr + k0 + 4);
    bf16x8 a;
    a[0] = (__bf16)af0[0]; a[1] = (__bf16)af0[1];
    a[2] = (__bf16)af0[2]; a[3] = (__bf16)af0[3];
    a[4] = (__bf16)af1[0]; a[5] = (__bf16)af1[1];
    a[6] = (__bf16)af1[2]; a[7] = (__bf16)af1[3];
    const __bf16* bp = wr + k0;
#pragma unroll
    for (int t = 0; t < NT; ++t) {
      bf16x8 b = *(const bf16x8*)(bp + (size_t)t * 16 * SEQP);
      acc[t] = __builtin_amdgcn_mfma_f32_16x16x32_bf16(a, b, acc[t], 0, 0, 0);
    }
  }

  // Tail: k0 = 704 covers k 704..735; only q<2 lanes have valid x (720 is a 16B-granule boundary).
  {
    const int k0 = 704;
    floatx4 af0 = (floatx4){0.f, 0.f, 0.f, 0.f};
    floatx4 af1 = (floatx4){0.f, 0.f, 0.f, 0.f};
    if (k0 + klane < SEQ)     af0 = *(const floatx4*)(xr + k0);
    if (k0 + klane + 4 < SEQ) af1 = *(const floatx4*)(xr + k0 + 4);
    bf16x8 a;
    a[0] = (__bf16)af0[0]; a[1] = (__bf16)af0[1];
    a[2] = (__bf16)af0[2]; a[3] = (__bf16)af0[3];
    a[4] = (__bf16)af1[0]; a[5] = (__bf16)af1[1];
    a[6] = (__bf16)af1[2]; a[7] = (__bf16)af1[3];
    const __bf16* bp = wr + k0;   // Wb zero-padded past 720 -> contributes 0
#pragma unroll
    for (int t = 0; t < NT; ++t) {
      bf16x8 b = *(const bf16x8*)(bp + (size_t)t * 16 * SEQP);
      acc[t] = __builtin_amdgcn_mfma_f32_16x16x32_bf16(a, b, acc[t], 0, 0, 0);
    }
  }

  // ---- epilogue: bias add + store. C/D layout: col=ln (p), row=q*4+r (batch) ----
  const float* bc = bias + cl * PRED;
#pragma unroll
  for (int t = 0; t < NT; ++t) {
    int p = (t << 4) + ln;
    float bv = bc[p];
#pragma unroll
    for (int r = 0; r < 4; ++r) {
      int brow = (wave << 4) + (q << 2) + r;    // batch index
      out[((size_t)brow * C_IN + c) * PRED + p] = acc[t][r] + bv;
    }
  }
}

extern "C" void kernel_launch(void* const* d_in, const int* in_sizes, int n_in,
                              void* d_out, int out_size, void* d_ws, size_t ws_size,
                              hipStream_t stream) {
  const float* x   = (const float*)d_in[0];
  const int*   cls = (const int*)d_in[1];
  const float* W   = (const float*)d_in[2];
  const float* b   = (const float*)d_in[3];
  float* out = (float*)d_out;
  __bf16* Wb = (__bf16*)d_ws;   // 8*336*768*2 = 4,128,768 B

  hipLaunchKernelGGL(wconv_kernel, dim3(N_CL * PRED), dim3(256), 0, stream, W, Wb);
  hipLaunchKernelGGL(clin_kernel, dim3(C_IN), dim3(256), 0, stream,
                     x, cls, Wb, b, out);
}

// Round 2
// 314.188 us; speedup vs baseline: 1.4290x; 1.4290x over previous
//
#include <hip/hip_runtime.h>
#include <stdint.h>

#define N_CL    8
#define C_IN    862
#define SEQ     720
#define SEQP    768            // K padded to 12 x 64 (Wb zero-padded)
#define PRED    336
#define BATCH   64
#define BK      32             // K-step per chunk (one 16x16x32 MFMA deep)
#define NCHUNK  23             // chunks cover k < 736; k>=720 hits Wb zero-pad
#define NT      (PRED / 16)    // 21 n-tiles per channel
#define XBSTRIDE ((size_t)C_IN * SEQ)   // x stride between batches (elements)

#define BROWS   384            // B rows staged per chunk, padded 336 -> 384
#define BBYTES  (BROWS * 64)   // 24576 B per buffer (64 B/row at BK=32)
#define NBISS   24             // 24 issues of 1024 B -> exactly 6 per wave

typedef __attribute__((ext_vector_type(8))) __bf16 bf16x8;
typedef __attribute__((ext_vector_type(4))) float  floatx4;

__device__ __forceinline__ void async16(const void* g, void* l) {
  __builtin_amdgcn_global_load_lds(
      (__attribute__((address_space(1))) unsigned int*)(uintptr_t)g,
      (__attribute__((address_space(3))) unsigned int*)l,
      16, 0, 0);
}

// ---- Kernel 1: W fp32 [8][336][720] -> bf16 [8][336][768] (zero-padded K) ----
__global__ void wconv_kernel(const float* __restrict__ W, __bf16* __restrict__ Wb) {
  const int row = blockIdx.x;                 // 0 .. 8*336-1
  const float* src = W + (size_t)row * SEQ;
  __bf16* dst = Wb + (size_t)row * SEQP;
  for (int s = threadIdx.x; s < SEQP; s += blockDim.x) {
    float v = (s < SEQ) ? src[s] : 0.0f;
    dst[s] = (__bf16)v;
  }
}

// ---- Kernel 2: per-channel GEMM, B double-buffered in LDS (counted vmcnt),
//      A wave-private in registers with 1-chunk-ahead prefetch. ----
// Per chunk (BK=32): stage next B tile (6 global_load_lds/wave) + load next A
// frags (2 loads/wave) -> s_waitcnt vmcnt(8) (current chunk's 8 done, next 8
// stay in flight across the barrier) -> s_barrier -> 21 ds_read_b128 + 21 MFMA
// -> s_barrier. No vmcnt(0) drain in the main loop.
__global__ __launch_bounds__(256, 3) void clin_kernel(
    const float* __restrict__ x, const int* __restrict__ clusters,
    const __bf16* __restrict__ Wb, const float* __restrict__ bias,
    float* __restrict__ out) {
  __shared__ __attribute__((aligned(128))) unsigned char smem[2 * BBYTES];

  const int c    = blockIdx.x;
  const int cl   = clusters[c];
  const int tid  = threadIdx.x;
  const int wave = tid >> 6;
  const int lane = tid & 63;
  const int q    = lane >> 4;     // quad 0..3 -> k-subgroup (k offset q*8)
  const int ln   = lane & 15;     // lane-in-quad -> m-row (A) / n-col (B)

  const int mrow  = (wave << 4) + ln;   // batch row 0..63
  const int klane = q << 3;             // per-lane k offset within 32-wide step

  const float*  xr = x  + (size_t)mrow * XBSTRIDE + (size_t)c * SEQ + klane;
  const __bf16* wc = Wb + (size_t)cl * PRED * SEQP;

  // ---- staging constants (lane-fixed) ----
  // Issue i writes LDS bytes [i*1024 + lane*16): physical row = i*16 + (lane>>2),
  // physical 16B slot = lane&3. Slot p of row r holds logical k-granule p^(r&3);
  // r&3 == (lane>>2)&3, so the source granule is lane-constant:
  const int srow  = lane >> 2;                         // row within issue
  const int sgran = (lane & 3) ^ ((lane >> 2) & 3);    // logical k-granule
  // Read side: row n, logical granule q lives at slot q^(n&3) -> bijection on
  // each 1 KB region -> linear-equivalent (conflict-free) ds_read_b128.
  const int brd = ln * 64 + (((q ^ (ln & 3)) & 3) << 4);  // per-lane read offset

  floatx4 acc[NT];
#pragma unroll
  for (int t = 0; t < NT; ++t) acc[t] = (floatx4){0.f, 0.f, 0.f, 0.f};

  // ---- helpers (macros to keep everything in registers / static) ----
#define STAGE_B(k0, Bdst)                                                    \
  {                                                                          \
    _Pragma("unroll")                                                        \
    for (int i = wave; i < NBISS; i += 4) {                                  \
      int r  = (i << 4) + srow;                                              \
      int rs = (r < PRED) ? r : 0;   /* pad rows: harmless in-bounds src */  \
      async16(wc + (size_t)rs * SEQP + (k0) + (sgran << 3), (Bdst) + i * 1024); \
    }                                                                        \
  }

  // A tail: k>=720 lanes clamp the ADDRESS to a valid one; their products hit
  // Wb's zero-pad so the garbage value is multiplied by 0. Loads always issue
  // (no exec masking) -> per-wave vmcnt stays uniform.
#define LOAD_A(k0, f0, f1)                                                   \
  {                                                                          \
    const float* ap = ((k0) + klane < SEQ) ? (xr + (k0)) : xr;               \
    f0 = *(const floatx4*)ap;                                                \
    f1 = *(const floatx4*)(ap + 4);                                          \
  }

#define COMPUTE(Bsrc, f0, f1)                                                \
  {                                                                          \
    bf16x8 a;                                                                \
    a[0] = (__bf16)f0[0]; a[1] = (__bf16)f0[1];                              \
    a[2] = (__bf16)f0[2]; a[3] = (__bf16)f0[3];                              \
    a[4] = (__bf16)f1[0]; a[5] = (__bf16)f1[1];                              \
    a[6] = (__bf16)f1[2]; a[7] = (__bf16)f1[3];                              \
    _Pragma("unroll")                                                        \
    for (int tt = 0; tt < NT; ++tt) {                                        \
      bf16x8 b = *(const bf16x8*)((Bsrc) + tt * 1024 + brd);                 \
      acc[tt] = __builtin_amdgcn_mfma_f32_16x16x32_bf16(a, b, acc[tt], 0, 0, 0); \
    }                                                                        \
  }

  unsigned char* const Bbuf0 = smem;
  unsigned char* const Bbuf1 = smem + BBYTES;

  floatx4 a0c, a1c, a0n, a1n;

  // ---- prologue: chunk 0 in flight ----
  STAGE_B(0, Bbuf0);
  LOAD_A(0, a0c, a1c);

  // ---- main loop: compute chunk t, prefetch chunk t+1 ----
#pragma unroll 2
  for (int t = 0; t < NCHUNK - 1; ++t) {
    unsigned char* Bc = (t & 1) ? Bbuf1 : Bbuf0;
    unsigned char* Bn = (t & 1) ? Bbuf0 : Bbuf1;
    const int k0n = (t + 1) * BK;

    STAGE_B(k0n, Bn);          // 6 issues/wave into the other buffer
    LOAD_A(k0n, a0n, a1n);     // 2 loads/wave into registers

    // Drain exactly chunk t's 8 vmem ops; chunk t+1's 8 stay in flight.
    asm volatile("s_waitcnt vmcnt(8)" ::: "memory");
    __builtin_amdgcn_s_barrier();

    COMPUTE(Bc, a0c, a1c);

    __builtin_amdgcn_s_barrier();   // all waves done reading Bc before t+2 overwrites it
    a0c = a0n; a1c = a1n;
  }

  // ---- epilogue chunk 22 (no prefetch behind it -> full drain is fine) ----
  asm volatile("s_waitcnt vmcnt(0)" ::: "memory");
  __builtin_amdgcn_s_barrier();
  {
    unsigned char* Bc = ((NCHUNK - 1) & 1) ? Bbuf1 : Bbuf0;
    COMPUTE(Bc, a0c, a1c);
  }

  // ---- epilogue: bias add + store. C/D layout: col=ln (p), row=q*4+r (batch) ----
  const float* bc = bias + cl * PRED;
#pragma unroll
  for (int t = 0; t < NT; ++t) {
    int p = (t << 4) + ln;
    float bv = bc[p];
#pragma unroll
    for (int r = 0; r < 4; ++r) {
      int brow = (wave << 4) + (q << 2) + r;    // batch index
      out[((size_t)brow * C_IN + c) * PRED + p] = acc[t][r] + bv;
    }
  }
#undef STAGE_B
#undef LOAD_A
#undef COMPUTE
}

extern "C" void kernel_launch(void* const* d_in, const int* in_sizes, int n_in,
                              void* d_out, int out_size, void* d_ws, size_t ws_size,
                              hipStream_t stream) {
  const float* x   = (const float*)d_in[0];
  const int*   cls = (const int*)d_in[1];
  const float* W   = (const float*)d_in[2];
  const float* b   = (const float*)d_in[3];
  float* out = (float*)d_out;
  __bf16* Wb = (__bf16*)d_ws;   // 8*336*768*2 = 4,128,768 B

  hipLaunchKernelGGL(wconv_kernel, dim3(N_CL * PRED), dim3(256), 0, stream, W, Wb);
  hipLaunchKernelGGL(clin_kernel, dim3(C_IN), dim3(256), 0, stream,
                     x, cls, Wb, b, out);
}